// Round 8
// baseline (36.654 us; speedup 1.0000x reference)
//
#include <hip/hip_runtime.h>
#include <math.h>

#define B_  4
#define CI  8
#define HH  128
#define WW  128
#define CO  16
#define KH  5
#define KW  5
#define HO  124
#define WO  124

#define TX  32
#define TY  8
#define THREADS 512   // 8 tx-groups * 8 rows * 8 waves; each wave owns ONE o
#define REPS 4        // DIAGNOSTIC: idempotent body reps (max(x,x)=x) to split
                      // fixed overhead vs true body time: body=(dur-15.09)/3

__global__ __launch_bounds__(THREADS, 4)
void maxplus_conv8(const float* __restrict__ img,
                   const float* __restrict__ kern,
                   float* __restrict__ out)
{
    // img tile rows y0..y0+11, cols x0..x0+35, -INF padded. [8][12][36] = 13.8 KB
    __shared__ __align__(16) float ilds[CI][TY + KH - 1][TX + KW - 1];

    const int tid   = threadIdx.x;
    const int x0    = blockIdx.x * TX;
    const int y0    = blockIdx.y * TY;
    const int bz    = blockIdx.z;        // b*2 + ohalf
    const int b     = bz >> 1;
    const int ohalf = bz & 1;

    // ---- stage img tile as float4 chunks: 8c * 12r * 9 float4 = 864 ----
    const float* imgb = img + (size_t)b * CI * HH * WW;
    #pragma unroll
    for (int it = 0; it < 2; ++it) {
        const int idx = tid + it * THREADS;
        if (idx < 864) {
            const int c   = idx / 108;
            const int rem = idx - c * 108;
            const int r   = rem / 9;
            const int f4  = rem - r * 9;
            const int gy = y0 + r;
            const int gx = x0 + f4 * 4;
            float4 v;
            if (gy < HH && gx < WW) {
                v = *(const float4*)&imgb[(c * HH + gy) * WW + gx];
            } else {
                v.x = v.y = v.z = v.w = -INFINITY;
            }
            *(float4*)&ilds[c][r][f4 * 4] = v;
        }
    }
    __syncthreads();

    const int tx = tid & 7;          // 4 px each
    const int ty = (tid >> 3) & 7;   // output row
    const int o = __builtin_amdgcn_readfirstlane(ohalf * 8 + (tid >> 6));

    const float* wp = kern + (size_t)o * (CI * KH * KW);

    float acc[4];
    #pragma unroll
    for (int p = 0; p < 4; ++p) acc[p] = -INFINITY;

    #pragma unroll 1
    for (int rep = 0; rep < REPS; ++rep) {
        // opaque per-rep copies: compiler cannot prove reps redundant -> full re-execution
        const float* wpo = wp;
        int tyo = ty;
        asm volatile("" : "+s"(wpo), "+v"(tyo));

        #pragma unroll 1
        for (int c = 0; c < CI; ++c) {
            float w[25];
            #pragma unroll
            for (int t = 0; t < 25; ++t) w[t] = wpo[c * 25 + t];
            float4 va[5], vb[5];
            #pragma unroll
            for (int i = 0; i < KH; ++i) {
                const float* vp = &ilds[c][tyo + i][tx * 4];
                va[i] = *(const float4*)vp;
                vb[i] = *(const float4*)(vp + 4);
            }
            #pragma unroll
            for (int i = 0; i < KH; ++i) {
                const float v[8] = {va[i].x, va[i].y, va[i].z, va[i].w,
                                    vb[i].x, vb[i].y, vb[i].z, vb[i].w};
                #pragma unroll
                for (int p = 0; p < 4; ++p) {
                    float T[5];
                    #pragma unroll
                    for (int j = 0; j < KW; ++j) {
                        const int wi = (4 - i) * KW + (4 - j);   // flipped tap
                        T[j] = v[p + j] + w[wi];
                    }
                    const float m0 = fmaxf(fmaxf(acc[p], T[0]), T[1]);  // v_max3
                    const float m1 = fmaxf(fmaxf(T[2], T[3]), T[4]);    // v_max3
                    acc[p] = fmaxf(m0, m1);
                }
            }
        }
    }

    const int y = y0 + ty;
    const int x = x0 + tx * 4;
    if (y < HO && x < WO) {
        float4 s;
        s.x = acc[0]; s.y = acc[1]; s.z = acc[2]; s.w = acc[3];
        *(float4*)&out[(((size_t)b * CO + o) * HO + y) * WO + x] = s;
    }
}

extern "C" void kernel_launch(void* const* d_in, const int* in_sizes, int n_in,
                              void* d_out, int out_size, void* d_ws, size_t ws_size,
                              hipStream_t stream)
{
    const float* img  = (const float*)d_in[0];
    const float* kern = (const float*)d_in[1];
    float* out = (float*)d_out;

    dim3 grid((WO + TX - 1) / TX, (HO + TY - 1) / TY, B_ * 2);  // 4 x 16 x 8 = 512 blocks
    dim3 block(THREADS);
    maxplus_conv8<<<grid, block, 0, stream>>>(img, kern, out);
}

// Round 9
// 17.534 us; speedup vs baseline: 2.0904x; 2.0904x over previous
//
#include <hip/hip_runtime.h>
#include <math.h>

#define B_  4
#define CI  8
#define HH  128
#define WW  128
#define CO  16
#define KH  5
#define KW  5
#define HO  124
#define WO  124

#define TX  32
#define TY  8
#define ROWF 44       // padded row length in floats (was 36): distinct bank starts, 16B aligned
#define THREADS 512   // 8 tx-groups * 8 rows * 8 waves; each wave owns ONE o

__device__ __forceinline__ float max3f(float a, float b, float c) {
    float d;
    asm("v_max3_f32 %0, %1, %2, %3" : "=v"(d) : "v"(a), "v"(b), "v"(c));
    return d;
}

__global__ __launch_bounds__(THREADS, 4)
void maxplus_conv9(const float* __restrict__ img,
                   const float* __restrict__ kern,
                   float* __restrict__ out)
{
    // img tile rows y0..y0+11, cols x0..x0+35 (of 44 padded), -INF outside img.
    __shared__ __align__(16) float ilds[CI][TY + KH - 1][ROWF]; // 8*12*44*4 = 16.9 KB

    const int tid   = threadIdx.x;
    const int x0    = blockIdx.x * TX;
    const int y0    = blockIdx.y * TY;
    const int bz    = blockIdx.z;        // b*2 + ohalf
    const int b     = bz >> 1;
    const int ohalf = bz & 1;

    // ---- stage img tile as float4 chunks: 8c * 12r * 9 float4 = 864 ----
    const float* imgb = img + (size_t)b * CI * HH * WW;
    #pragma unroll
    for (int it = 0; it < 2; ++it) {
        const int idx = tid + it * THREADS;
        if (idx < 864) {
            const int c   = idx / 108;
            const int rem = idx - c * 108;
            const int r   = rem / 9;
            const int f4  = rem - r * 9;
            const int gy = y0 + r;
            const int gx = x0 + f4 * 4;
            float4 v;
            if (gy < HH && gx < WW) {
                v = *(const float4*)&imgb[(c * HH + gy) * WW + gx];
            } else {
                v.x = v.y = v.z = v.w = -INFINITY;
            }
            *(float4*)&ilds[c][r][f4 * 4] = v;
        }
    }
    __syncthreads();

    const int tx = tid & 7;          // 4 px each
    const int ty = (tid >> 3) & 7;   // output row
    const int o = __builtin_amdgcn_readfirstlane(ohalf * 8 + (tid >> 6));

    const float* wp = kern + (size_t)o * (CI * KH * KW);

    float acc[4];
    #pragma unroll
    for (int p = 0; p < 4; ++p) acc[p] = -INFINITY;

    #pragma unroll 1
    for (int c = 0; c < CI; ++c) {
        float w[25];
        #pragma unroll
        for (int t = 0; t < 25; ++t) w[t] = wp[c * 25 + t];
        float4 va[5], vb[5];
        #pragma unroll
        for (int i = 0; i < KH; ++i) {
            const float* vp = &ilds[c][ty + i][tx * 4];
            va[i] = *(const float4*)vp;
            vb[i] = *(const float4*)(vp + 4);
        }
        #pragma unroll
        for (int i = 0; i < KH; ++i) {
            const float v[8] = {va[i].x, va[i].y, va[i].z, va[i].w,
                                vb[i].x, vb[i].y, vb[i].z, vb[i].w};
            #pragma unroll
            for (int p = 0; p < 4; ++p) {
                float T[5];
                #pragma unroll
                for (int j = 0; j < KW; ++j) {
                    const int wi = (4 - i) * KW + (4 - j);   // flipped tap
                    T[j] = v[p + j] + w[wi];
                }
                // 6 values (acc + 5 taps) -> 2 parallel max3 + 1 max = 3 ops, depth 2
                acc[p] = fmaxf(max3f(T[0], T[1], T[2]), max3f(T[3], T[4], acc[p]));
            }
        }
    }

    const int y = y0 + ty;
    const int x = x0 + tx * 4;
    if (y < HO && x < WO) {
        float4 s;
        s.x = acc[0]; s.y = acc[1]; s.z = acc[2]; s.w = acc[3];
        *(float4*)&out[(((size_t)b * CO + o) * HO + y) * WO + x] = s;
    }
}

extern "C" void kernel_launch(void* const* d_in, const int* in_sizes, int n_in,
                              void* d_out, int out_size, void* d_ws, size_t ws_size,
                              hipStream_t stream)
{
    const float* img  = (const float*)d_in[0];
    const float* kern = (const float*)d_in[1];
    float* out = (float*)d_out;

    dim3 grid((WO + TX - 1) / TX, (HO + TY - 1) / TY, B_ * 2);  // 4 x 16 x 8 = 512 blocks
    dim3 block(THREADS);
    maxplus_conv9<<<grid, block, 0, stream>>>(img, kern, out);
}

// Round 10
// 14.978 us; speedup vs baseline: 2.4472x; 1.1707x over previous
//
#include <hip/hip_runtime.h>
#include <math.h>

#define B_  4
#define CI  8
#define HH  128
#define WW  128
#define CO  16
#define KH  5
#define KW  5
#define HO  124
#define WO  124

#define TX  32
#define TY  8
#define THREADS 512   // 8 tx-groups * 8 rows * 8 waves; each wave owns ONE o

__global__ __launch_bounds__(THREADS, 4)
void maxplus_conv10(const float* __restrict__ img,
                    const float* __restrict__ kern,
                    float* __restrict__ out)
{
    // img tile rows y0..y0+11, cols x0..x0+35, -INF padded. [8][12][36] = 13.8 KB
    __shared__ __align__(16) float ilds[CI][TY + KH - 1][TX + KW - 1];

    const int tid   = threadIdx.x;
    const int x0    = blockIdx.x * TX;
    const int y0    = blockIdx.y * TY;
    const int bz    = blockIdx.z;        // b*2 + ohalf
    const int b     = bz >> 1;
    const int ohalf = bz & 1;

    // ---- stage img tile as float4 chunks: 8c * 12r * 9 float4 = 864 ----
    const float* imgb = img + (size_t)b * CI * HH * WW;
    #pragma unroll
    for (int it = 0; it < 2; ++it) {
        const int idx = tid + it * THREADS;
        if (idx < 864) {
            const int c   = idx / 108;
            const int rem = idx - c * 108;
            const int r   = rem / 9;
            const int f4  = rem - r * 9;
            const int gy = y0 + r;
            const int gx = x0 + f4 * 4;
            float4 v;
            if (gy < HH && gx < WW) {
                v = *(const float4*)&imgb[(c * HH + gy) * WW + gx];
            } else {
                v.x = v.y = v.z = v.w = -INFINITY;
            }
            *(float4*)&ilds[c][r][f4 * 4] = v;
        }
    }
    __syncthreads();

    const int tx = tid & 7;          // 4 px each
    const int ty = (tid >> 3) & 7;   // output row
    const int o = __builtin_amdgcn_readfirstlane(ohalf * 8 + (tid >> 6));

    const float* wp = kern + (size_t)o * (CI * KH * KW);

    float acc[4];
    #pragma unroll
    for (int p = 0; p < 4; ++p) acc[p] = -INFINITY;

    // 2-deep weight pipeline: static A/B arrays (compile-time indexed only).
    float wA[25], wB[25];
    #pragma unroll
    for (int t = 0; t < 25; ++t) wA[t] = wp[t];          // c = 0

    // compute one channel with the given (already-loaded) weight array
#define COMPUTE(c, W) do { \
    _Pragma("unroll") \
    for (int i = 0; i < KH; ++i) { \
        const float* vp = &ilds[c][ty + i][tx * 4]; \
        const float4 va = *(const float4*)vp; \
        const float4 vb = *(const float4*)(vp + 4); \
        const float v[8] = {va.x, va.y, va.z, va.w, vb.x, vb.y, vb.z, vb.w}; \
        _Pragma("unroll") \
        for (int p = 0; p < 4; ++p) { \
            float T[5]; \
            _Pragma("unroll") \
            for (int j = 0; j < KW; ++j) { \
                T[j] = v[p + j] + W[(4 - i) * KW + (4 - j)]; /* flipped tap */ \
            } \
            const float m0 = fmaxf(fmaxf(acc[p], T[0]), T[1]);  /* v_max3 */ \
            const float m1 = fmaxf(fmaxf(T[2], T[3]), T[4]);    /* v_max3 */ \
            acc[p] = fmaxf(m0, m1); \
        } \
    } } while (0)

    #pragma unroll 1
    for (int cp = 0; cp < CI / 2; ++cp) {
        const int c0 = 2 * cp;
        // prefetch weights for c0+1 (c0+1 <= 7, always valid)
        #pragma unroll
        for (int t = 0; t < 25; ++t) wB[t] = wp[(c0 + 1) * 25 + t];
        COMPUTE(c0, wA);
        // prefetch weights for c0+2 (clamped on last iter: harmless redundant load)
        const int cn = (c0 + 2 < CI) ? (c0 + 2) : (CI - 1);
        #pragma unroll
        for (int t = 0; t < 25; ++t) wA[t] = wp[cn * 25 + t];
        COMPUTE(c0 + 1, wB);
    }
#undef COMPUTE

    // ---- write out: one float4 ----
    const int y = y0 + ty;
    const int x = x0 + tx * 4;
    if (y < HO && x < WO) {
        float4 s;
        s.x = acc[0]; s.y = acc[1]; s.z = acc[2]; s.w = acc[3];
        *(float4*)&out[(((size_t)b * CO + o) * HO + y) * WO + x] = s;
    }
}

extern "C" void kernel_launch(void* const* d_in, const int* in_sizes, int n_in,
                              void* d_out, int out_size, void* d_ws, size_t ws_size,
                              hipStream_t stream)
{
    const float* img  = (const float*)d_in[0];
    const float* kern = (const float*)d_in[1];
    float* out = (float*)d_out;

    dim3 grid((WO + TX - 1) / TX, (HO + TY - 1) / TY, B_ * 2);  // 4 x 16 x 8 = 512 blocks
    dim3 block(THREADS);
    maxplus_conv10<<<grid, block, 0, stream>>>(img, kern, out);
}